// Round 6
// baseline (473.839 us; speedup 1.0000x reference)
//
#include <hip/hip_runtime.h>
#include <math.h>

#define NUM_LAYERS 3
#define KCB 2048        // codebook size
#define DIM 256         // embed dim
#define NROWS 32768     // B*T
#define NQ (NROWS * DIM)

// d_ws layout: F = fp16 codebook fragments for 32x32x16 MFMA.
//   per layer 2 MB: team t (1 MB) -> tile c in [0,32) (32 KB) -> ks in [0,16) (2 KB = hi 1K | lo 1K)
//   within a 1 KB half: lane*16 B, element j: W[t*1024 + c*32 + (lane&31)][ks*16 + (lane>>5)*8 + j]
//   wsq (fp32 ||w||^2, 3*2048) at byte offset F_BYTES.
#define F_BYTES (3u * 2097152u)   // 6,291,456

// dynamic LDS partition (bytes)
#define BSH_OFF  0          // 2 bufs x [2 teams][32768] = 131072
#define RSQ_OFF  131072     // 128 rows x f32 = 512
#define BV_OFF   131584     // 8 waves x 32 rows x f32 = 1024
#define BI_OFF   132608     // 8 x 32 x i32 = 1024
#define BIDX_OFF 133632     // 128 x i32 = 512
#define SMEM_BYTES 134144

typedef _Float16 half8 __attribute__((ext_vector_type(8)));
typedef float   f32x16 __attribute__((ext_vector_type(16)));

// ---------------- prep: ||w||^2 (unchanged, verified) ----------------
__global__ void rvq_wsq(const float* __restrict__ cb, float* __restrict__ wsq)
{
    int tid = blockIdx.x * 256 + threadIdx.x;   // 0 .. 6143
    const float* p = cb + (size_t)tid * DIM;
    float s = 0.f;
    #pragma unroll
    for (int u = 0; u < 64; ++u) {
        float4 v = *(const float4*)(p + u * 4);
        s = fmaf(v.x, v.x, s); s = fmaf(v.y, v.y, s);
        s = fmaf(v.z, v.z, s); s = fmaf(v.w, v.w, s);
    }
    wsq[tid] = s;
}

// ---------------- prep: fp16 hi/lo fragment repack (32x32x16 B layout) ----------------
// grid: 3 layers x 2 teams x 32 tiles x 16 ks = 3072 blocks of 64 threads
__global__ void rvq_repack(const float* __restrict__ cb, unsigned short* __restrict__ F)
{
    int b = blockIdx.x;
    int layer = b >> 10;          // /1024
    int rem   = b & 1023;
    int team  = rem >> 9;
    int c     = (rem >> 4) & 31;
    int ks    = rem & 15;
    int lane  = threadIdx.x;

    int cw = team * 1024 + c * 32 + (lane & 31);
    int k0 = ks * 16 + (lane >> 5) * 8;
    const float* src = cb + ((size_t)(layer * KCB + cw)) * DIM + k0;
    float4 x0 = *(const float4*)(src);
    float4 x1 = *(const float4*)(src + 4);
    float v[8] = {x0.x, x0.y, x0.z, x0.w, x1.x, x1.y, x1.z, x1.w};

    half8 hi, lo;
    #pragma unroll
    for (int j = 0; j < 8; ++j) {
        _Float16 h = (_Float16)v[j];
        hi[j] = h;
        lo[j] = (_Float16)(v[j] - (float)h);
    }
    size_t base = ((size_t)b) * 1024;   // ushort units (2048 B per (layer,team,c,ks))
    *(half8*)(F + base + lane * 8)        = hi;
    *(half8*)(F + base + 512 + lane * 8)  = lo;
}

// ---------------- async stage of one 64 KB chunk (tile c of both teams) ----------------
__device__ __forceinline__ void stage_chunk(const char* Fb, char* Bsh,
                                            int c, int buf, int wv, int lane)
{
    #pragma unroll
    for (int i = 0; i < 8; ++i) {
        int s = wv * 8 + i;
        int tm = s >> 5;            // team region
        int off = (s & 31) * 1024;  // within the 32 KB tile
        const char* g = Fb + (size_t)tm * 1048576 + (size_t)c * 32768 + off + (size_t)lane * 16;
        char* lp = Bsh + (size_t)buf * 65536 + (size_t)tm * 32768 + off + (size_t)lane * 16;
        __builtin_amdgcn_global_load_lds(
            (const __attribute__((address_space(1))) unsigned int*)g,
            (__attribute__((address_space(3))) unsigned int*)lp, 16, 0, 0);
    }
}

// ---------------- main fused RVQ ----------------
// 512 thr = 8 waves: wave = rgroup(0..3)*2 + team(0..1). 128 rows/block, grid 256
// (1 block/CU, 2 waves/SIMD). Residual = fp16 hi/lo 32x32x16 A fragments in registers.
__global__ __launch_bounds__(512, 2)
void rvq_main(const float* __restrict__ h,
              const float* __restrict__ cb,
              const unsigned short* __restrict__ F,
              const float* __restrict__ wsq,
              float* __restrict__ out)
{
    extern __shared__ char smem[];
    char*  Bsh     = smem + BSH_OFF;
    float* rsq_sh  = (float*)(smem + RSQ_OFF);
    float* bV_sh   = (float*)(smem + BV_OFF);
    int*   bI_sh   = (int*)  (smem + BI_OFF);
    int*   bidx_sh = (int*)  (smem + BIDX_OFF);

    const int t      = threadIdx.x;
    const int lane   = t & 63;
    const int wv     = t >> 6;
    const int team   = wv & 1;        // codeword half (0: cw<1024)
    const int rgroup = wv >> 1;       // row group (32 rows each)
    const int rowB   = blockIdx.x * 128;
    const int row0w  = rowB + rgroup * 32;
    const int ln     = lane & 31;     // A row / C col within tile
    const int lh     = lane >> 5;     // k-half selector

    // ---- residual fragments (fp16 hi/lo, 32x32x16 A layout) + partial ||r||^2 ----
    // lane holds A[row=ln][k = ks*16 + lh*8 + j]
    half8 ahi[16], alo[16];
    float s2 = 0.f;
    {
        const float* rp = h + (size_t)(row0w + ln) * DIM + lh * 8;
        #pragma unroll
        for (int ks = 0; ks < 16; ++ks) {
            float4 x0 = *(const float4*)(rp + ks * 16);
            float4 x1 = *(const float4*)(rp + ks * 16 + 4);
            float v[8] = {x0.x, x0.y, x0.z, x0.w, x1.x, x1.y, x1.z, x1.w};
            #pragma unroll
            for (int j = 0; j < 8; ++j) {
                _Float16 hv = (_Float16)v[j];
                ahi[ks][j] = hv;
                alo[ks][j] = (_Float16)(v[j] - (float)hv);
                s2 = fmaf(v[j], v[j], s2);
            }
        }
    }

    // ---- prefetch layer 0, chunk 0 into buf 0 ----
    stage_chunk((const char*)F, Bsh, 0, 0, wv, lane);

    for (int l = 0; l < NUM_LAYERS; ++l) {
        const float* __restrict__ Wl  = cb + (size_t)l * KCB * DIM;
        const float* __restrict__ wql = wsq + l * KCB;
        const char*  Fb = (const char*)F + (size_t)l * 2097152;

        // ---- complete ||r||^2 per row (combine the two k-halves), stage to LDS ----
        float rs = s2 + __shfl_xor(s2, 32);
        if (team == 0 && lh == 0) rsq_sh[rgroup * 32 + ln] = rs;
        __syncthreads();   // rsq_sh visible; chunk-0 staging drained

        // ---- per-lane rsq for the 16 C-rows: row(r) = (r&3) + 8*(r>>2) + 4*lh ----
        float rsqR[16];
        #pragma unroll
        for (int r = 0; r < 16; ++r)
            rsqR[r] = rsq_sh[rgroup * 32 + (r & 3) + 8 * (r >> 2) + 4 * lh];

        float bestV[16];
        int   bestI[16];
        #pragma unroll
        for (int r = 0; r < 16; ++r) { bestV[r] = INFINITY; bestI[r] = 0; }

        // ---- 32 chunks; each team computes its 32-cw tile, double-buffered ----
        for (int c = 0; c < 32; ++c) {
            const int cur = c & 1;
            if (c + 1 < 32) stage_chunk(Fb, Bsh, c + 1, 1 - cur, wv, lane);

            const char* base = Bsh + (size_t)cur * 65536 + (size_t)team * 32768;
            f32x16 acc0 = {}, acc1 = {};
            #pragma unroll
            for (int ks = 0; ks < 16; ++ks) {
                half8 bhi = *(const half8*)(base + ks * 2048 + lane * 16);
                half8 blo = *(const half8*)(base + ks * 2048 + 1024 + lane * 16);
                if (ks & 1) {
                    acc1 = __builtin_amdgcn_mfma_f32_32x32x16_f16(ahi[ks], bhi, acc1, 0, 0, 0);
                    acc1 = __builtin_amdgcn_mfma_f32_32x32x16_f16(alo[ks], bhi, acc1, 0, 0, 0);
                    acc1 = __builtin_amdgcn_mfma_f32_32x32x16_f16(ahi[ks], blo, acc1, 0, 0, 0);
                } else {
                    acc0 = __builtin_amdgcn_mfma_f32_32x32x16_f16(ahi[ks], bhi, acc0, 0, 0, 0);
                    acc0 = __builtin_amdgcn_mfma_f32_32x32x16_f16(alo[ks], bhi, acc0, 0, 0, 0);
                    acc0 = __builtin_amdgcn_mfma_f32_32x32x16_f16(ahi[ks], blo, acc0, 0, 0, 0);
                }
            }
            const int col = team * 1024 + c * 32 + ln;
            const float wq = wql[col];
            #pragma unroll
            for (int r = 0; r < 16; ++r) {
                float cc = acc0[r] + acc1[r];
                float dist = (rsqR[r] - 2.f * cc) + wq;
                if (dist < bestV[r]) { bestV[r] = dist; bestI[r] = col; }
            }
            __syncthreads();   // releases cur buf; drains next-chunk prefetch
        }

        // ---- argmin: reduce across the 32 cols (lanes within each half) ----
        #pragma unroll
        for (int r = 0; r < 16; ++r) {
            float bv = bestV[r]; int bi = bestI[r];
            #pragma unroll
            for (int s = 16; s; s >>= 1) {
                float ov = __shfl_xor(bv, s);
                int   oi = __shfl_xor(bi, s);
                if (ov < bv || (ov == bv && oi < bi)) { bv = ov; bi = oi; }
            }
            bestV[r] = bv; bestI[r] = bi;
        }
        if (ln == 0) {   // lanes 0 and 32: each half owns 16 rows
            #pragma unroll
            for (int r = 0; r < 16; ++r) {
                int row = (r & 3) + 8 * (r >> 2) + 4 * lh;
                bV_sh[wv * 32 + row] = bestV[r];
                bI_sh[wv * 32 + row] = bestI[r];
            }
        }
        __syncthreads();

        // ---- combine the two cw-teams per row, write index ----
        if (t < 128) {
            int rg = t >> 5, rl = t & 31;
            float v0 = bV_sh[(rg * 2 + 0) * 32 + rl]; int i0 = bI_sh[(rg * 2 + 0) * 32 + rl];
            float v1 = bV_sh[(rg * 2 + 1) * 32 + rl]; int i1 = bI_sh[(rg * 2 + 1) * 32 + rl];
            int bi = (v1 < v0 || (v1 == v0 && i1 < i0)) ? i1 : i0;
            bidx_sh[t] = bi;
            out[NQ + (size_t)l * NROWS + rowB + t] = (float)bi;
        }
        // prefetch next layer's chunk 0 (independent of bidx) into buf 0
        if (l < NUM_LAYERS - 1)
            stage_chunk(Fb + 2097152, Bsh, 0, 0, wv, lane);
        __syncthreads();   // bidx_sh visible

        if (l < NUM_LAYERS - 1) {
            // ---- residual update in registers: r <- (hi+lo) - w, re-split ----
            const int bi = bidx_sh[rgroup * 32 + ln];
            const float* wrow = Wl + (size_t)bi * DIM + lh * 8;
            float ns = 0.f;
            #pragma unroll
            for (int ks = 0; ks < 16; ++ks) {
                float4 w0 = *(const float4*)(wrow + ks * 16);
                float4 w1 = *(const float4*)(wrow + ks * 16 + 4);
                float wv8[8] = {w0.x, w0.y, w0.z, w0.w, w1.x, w1.y, w1.z, w1.w};
                #pragma unroll
                for (int j = 0; j < 8; ++j) {
                    float r = ((float)ahi[ks][j] + (float)alo[ks][j]) - wv8[j];
                    _Float16 hv = (_Float16)r;
                    ahi[ks][j] = hv;
                    alo[ks][j] = (_Float16)(r - (float)hv);
                    ns = fmaf(r, r, ns);
                }
            }
            s2 = ns;
        } else {
            // ---- final: out = h - (r2 - w3); team t handles ks in [t*8, t*8+8) ----
            const int row = row0w + ln;
            const int bi  = bidx_sh[rgroup * 32 + ln];
            const float* wrow = Wl + (size_t)bi * DIM + lh * 8;
            const float* hp   = h + (size_t)row * DIM + lh * 8;
            float* op         = out + (size_t)row * DIM + lh * 8;
            #pragma unroll
            for (int ksi = 0; ksi < 8; ++ksi) {
                const int ks = team * 8 + ksi;
                float4 w0 = *(const float4*)(wrow + ks * 16);
                float4 w1 = *(const float4*)(wrow + ks * 16 + 4);
                float4 h0 = *(const float4*)(hp + ks * 16);
                float4 h1 = *(const float4*)(hp + ks * 16 + 4);
                float wv8[8] = {w0.x, w0.y, w0.z, w0.w, w1.x, w1.y, w1.z, w1.w};
                float hv8[8] = {h0.x, h0.y, h0.z, h0.w, h1.x, h1.y, h1.z, h1.w};
                float o[8];
                #pragma unroll
                for (int j = 0; j < 8; ++j) {
                    float r = ((float)ahi[ks][j] + (float)alo[ks][j]) - wv8[j];
                    o[j] = hv8[j] - r;
                }
                *(float4*)(op + ks * 16)     = make_float4(o[0], o[1], o[2], o[3]);
                *(float4*)(op + ks * 16 + 4) = make_float4(o[4], o[5], o[6], o[7]);
            }
        }
    }
}

extern "C" void kernel_launch(void* const* d_in, const int* in_sizes, int n_in,
                              void* d_out, int out_size, void* d_ws, size_t ws_size,
                              hipStream_t stream) {
    const float* h  = (const float*)d_in[0];
    const float* cb = (const float*)d_in[1];
    float* out = (float*)d_out;
    unsigned short* F = (unsigned short*)d_ws;
    float* wsq = (float*)((char*)d_ws + F_BYTES);

    hipFuncSetAttribute((const void*)rvq_main,
                        hipFuncAttributeMaxDynamicSharedMemorySize, SMEM_BYTES);

    rvq_wsq   <<<dim3(24),   dim3(256), 0, stream>>>(cb, wsq);
    rvq_repack<<<dim3(3072), dim3(64),  0, stream>>>(cb, F);
    rvq_main  <<<dim3(NROWS / 128), dim3(512), SMEM_BYTES, stream>>>(h, cb, F, wsq, out);
}

// Round 7
// 374.494 us; speedup vs baseline: 1.2653x; 1.2653x over previous
//
#include <hip/hip_runtime.h>
#include <math.h>

#define NUM_LAYERS 3
#define KCB 2048        // codebook size
#define DIM 256         // embed dim
#define NROWS 32768     // B*T
#define NQ (NROWS * DIM)

// d_ws layout: F = fp16 codebook fragments (16x16x32 layout, same as round 5).
//   tile tn (16 cw) = 16384 B = 8 kb-blocks of [hi 1024 B | lo 1024 B]
//   within a 1024 B half: lane*16 B -> 8 halves: W[tn*16+(lane&15)][kb*32+(lane>>4)*8+j]
//   layer stride 2 MB. wsq (fp32 ||w||^2, 3*2048) at byte offset F_BYTES.
//   chunk c = 32 KB = tiles {2c, 2c+1} at Fb + c*32768.
#define F_BYTES (3u * 128u * 16384u)   // 6,291,456

// dynamic LDS partition (bytes)
#define BSH_OFF  0        // 2 bufs x 32768 (one 32-cw chunk each)
#define XCH_OFF  65536    // 2 bufs x [rg 0..3][writer-kteam 0..1][mi 0..1][lane*16B] = 2*16384
#define RSQP_OFF 98304    // [kteam 0..1][128 rows] f32 = 1024
#define BV_OFF   99328    // 8 waves x 32 rows f32 = 1024
#define BI_OFF   100352   // 8 x 32 i32 = 1024
#define BIDX_OFF 101376   // 128 i32 = 512
#define SMEM_BYTES 101888

typedef _Float16 half8 __attribute__((ext_vector_type(8)));
typedef float   f32x4 __attribute__((ext_vector_type(4)));

// ---------------- prep: ||w||^2 (unchanged, verified) ----------------
__global__ void rvq_wsq(const float* __restrict__ cb, float* __restrict__ wsq)
{
    int tid = blockIdx.x * 256 + threadIdx.x;   // 0 .. 6143
    const float* p = cb + (size_t)tid * DIM;
    float s = 0.f;
    #pragma unroll
    for (int u = 0; u < 64; ++u) {
        float4 v = *(const float4*)(p + u * 4);
        s = fmaf(v.x, v.x, s); s = fmaf(v.y, v.y, s);
        s = fmaf(v.z, v.z, s); s = fmaf(v.w, v.w, s);
    }
    wsq[tid] = s;
}

// ---------------- prep: fp16 hi/lo fragment repack (round-5 layout, verified) ----------------
__global__ void rvq_repack(const float* __restrict__ cb, unsigned short* __restrict__ F)
{
    int b = blockIdx.x;           // layer*1024 + tn*8 + kb
    int layer = b >> 10;
    int rem   = b & 1023;
    int tn    = rem >> 3;
    int kb    = rem & 7;
    int lane  = threadIdx.x;

    int cw = tn * 16 + (lane & 15);
    int k0 = kb * 32 + (lane >> 4) * 8;
    const float* src = cb + ((size_t)(layer * KCB + cw)) * DIM + k0;
    float4 x0 = *(const float4*)(src);
    float4 x1 = *(const float4*)(src + 4);
    float v[8] = {x0.x, x0.y, x0.z, x0.w, x1.x, x1.y, x1.z, x1.w};

    half8 hi, lo;
    #pragma unroll
    for (int j = 0; j < 8; ++j) {
        _Float16 h = (_Float16)v[j];
        hi[j] = h;
        lo[j] = (_Float16)(v[j] - (float)h);
    }
    size_t base = ((size_t)b) * 1024;   // ushort units (2048 B per (layer,tn,kb))
    *(half8*)(F + base + lane * 8)        = hi;
    *(half8*)(F + base + 512 + lane * 8)  = lo;
}

// ---------------- async stage of one 32 KB chunk ----------------
__device__ __forceinline__ void stage_chunk32(const char* Fb, char* dst, int c, int t)
{
    const char* g = Fb + (size_t)c * 32768;
    #pragma unroll
    for (int i = 0; i < 4; ++i) {
        int off = (i * 512 + t) * 16;
        __builtin_amdgcn_global_load_lds(
            (const __attribute__((address_space(1))) unsigned int*)(g + off),
            (__attribute__((address_space(3))) unsigned int*)(dst + off), 16, 0, 0);
    }
}

// ---------------- partial cross for one 16-cw tile over this wave's k-half ----------------
__device__ __forceinline__ void tile_partial(
    const char* tbase, const half8 (&ahi)[2][4], const half8 (&alo)[2][4],
    int kt, int lane, f32x4 (&po)[2])
{
    const f32x4 z = {0.f, 0.f, 0.f, 0.f};
    f32x4 a00 = z, a01 = z, a10 = z, a11 = z;
    #pragma unroll
    for (int kq = 0; kq < 4; ++kq) {
        const int kb = kt * 4 + kq;
        half8 bhi = *(const half8*)(tbase + kb * 2048 + lane * 16);
        half8 blo = *(const half8*)(tbase + kb * 2048 + 1024 + lane * 16);
        if (kq & 1) {
            a01 = __builtin_amdgcn_mfma_f32_16x16x32_f16(ahi[0][kq], bhi, a01, 0, 0, 0);
            a11 = __builtin_amdgcn_mfma_f32_16x16x32_f16(ahi[1][kq], bhi, a11, 0, 0, 0);
            a01 = __builtin_amdgcn_mfma_f32_16x16x32_f16(alo[0][kq], bhi, a01, 0, 0, 0);
            a11 = __builtin_amdgcn_mfma_f32_16x16x32_f16(alo[1][kq], bhi, a11, 0, 0, 0);
            a01 = __builtin_amdgcn_mfma_f32_16x16x32_f16(ahi[0][kq], blo, a01, 0, 0, 0);
            a11 = __builtin_amdgcn_mfma_f32_16x16x32_f16(ahi[1][kq], blo, a11, 0, 0, 0);
        } else {
            a00 = __builtin_amdgcn_mfma_f32_16x16x32_f16(ahi[0][kq], bhi, a00, 0, 0, 0);
            a10 = __builtin_amdgcn_mfma_f32_16x16x32_f16(ahi[1][kq], bhi, a10, 0, 0, 0);
            a00 = __builtin_amdgcn_mfma_f32_16x16x32_f16(alo[0][kq], bhi, a00, 0, 0, 0);
            a10 = __builtin_amdgcn_mfma_f32_16x16x32_f16(alo[1][kq], bhi, a10, 0, 0, 0);
            a00 = __builtin_amdgcn_mfma_f32_16x16x32_f16(ahi[0][kq], blo, a00, 0, 0, 0);
            a10 = __builtin_amdgcn_mfma_f32_16x16x32_f16(ahi[1][kq], blo, a10, 0, 0, 0);
        }
    }
    #pragma unroll
    for (int i = 0; i < 4; ++i) { po[0][i] = a00[i] + a01[i]; po[1][i] = a10[i] + a11[i]; }
}

// ---------------- main fused RVQ ----------------
// 512 thr = 8 waves: wave = rgroup(0..3)*2 + kteam(0..1). 128 rows/block, grid 256
// (1 block/CU, 2 waves/SIMD). Each wave holds its k-half of the residual hi/lo
// fragments (64 regs) -> no spills. Partial crosses exchanged through LDS.
__global__ __launch_bounds__(512, 2)
void rvq_main(const float* __restrict__ h,
              const float* __restrict__ cb,
              const unsigned short* __restrict__ F,
              const float* __restrict__ wsq,
              float* __restrict__ out)
{
    extern __shared__ char smem[];
    char*  Bsh     = smem + BSH_OFF;
    char*  Xch     = smem + XCH_OFF;
    float* rsqp    = (float*)(smem + RSQP_OFF);
    float* bV_sh   = (float*)(smem + BV_OFF);
    int*   bI_sh   = (int*)  (smem + BI_OFF);
    int*   bidx_sh = (int*)  (smem + BIDX_OFF);

    const int t     = threadIdx.x;
    const int lane  = t & 63;
    const int wv    = t >> 6;
    const int kt    = wv & 1;         // k-team: k in [kt*128, kt*128+128)
    const int rg    = wv >> 1;        // row group (32 rows each)
    const int rowB  = blockIdx.x * 128;
    const int row0w = rowB + rg * 32;
    const int arow  = lane & 15;      // A row / C col
    const int aq    = lane >> 4;      // k-quad / C row-quad

    // ---- residual fragments (fp16 hi/lo, k-half only) + partial ||r||^2 ----
    half8 ahi[2][4], alo[2][4];
    float s2[2];
    #pragma unroll
    for (int mi = 0; mi < 2; ++mi) {
        s2[mi] = 0.f;
        #pragma unroll
        for (int kq = 0; kq < 4; ++kq) {
            const float* p = h + (size_t)(row0w + mi * 16 + arow) * DIM + (kt * 4 + kq) * 32 + aq * 8;
            float4 x0 = *(const float4*)(p);
            float4 x1 = *(const float4*)(p + 4);
            float v[8] = {x0.x, x0.y, x0.z, x0.w, x1.x, x1.y, x1.z, x1.w};
            #pragma unroll
            for (int j = 0; j < 8; ++j) {
                _Float16 hv = (_Float16)v[j];
                ahi[mi][kq][j] = hv;
                alo[mi][kq][j] = (_Float16)(v[j] - (float)hv);
                s2[mi] = fmaf(v[j], v[j], s2[mi]);
            }
        }
    }

    // ---- prefetch layer 0, chunk 0 into buf 0 ----
    stage_chunk32((const char*)F, Bsh, 0, t);

    for (int l = 0; l < NUM_LAYERS; ++l) {
        const float* __restrict__ Wl  = cb + (size_t)l * KCB * DIM;
        const float* __restrict__ wql = wsq + l * KCB;
        const char*  Fb = (const char*)F + (size_t)l * 2097152;

        // ---- per-row ||r||^2: sum over aq in-wave, publish k-half partials ----
        float a0 = s2[0], a1 = s2[1];
        a0 += __shfl_xor(a0, 16); a0 += __shfl_xor(a0, 32);
        a1 += __shfl_xor(a1, 16); a1 += __shfl_xor(a1, 32);
        if (aq == 0) {
            rsqp[kt * 128 + rg * 32 + arow]      = a0;
            rsqp[kt * 128 + rg * 32 + 16 + arow] = a1;
        }
        __syncthreads();   // rsqp visible; chunk-0 staging drained

        float rsqC[2][4];
        #pragma unroll
        for (int mi = 0; mi < 2; ++mi)
            #pragma unroll
            for (int i = 0; i < 4; ++i) {
                int row = rg * 32 + mi * 16 + aq * 4 + i;
                rsqC[mi][i] = rsqp[row] + rsqp[128 + row];
            }

        float bestV[2][4];
        int   bestI[2][4];
        #pragma unroll
        for (int mi = 0; mi < 2; ++mi)
            #pragma unroll
            for (int i = 0; i < 4; ++i) { bestV[mi][i] = INFINITY; bestI[mi][i] = 0; }

        // ---- 64 chunks of 32 cw (tiles 2c, 2c+1), one barrier per chunk ----
        for (int c = 0; c < 64; ++c) {
            const int cur = c & 1;
            if (c + 1 < 64) stage_chunk32(Fb, Bsh + (size_t)(1 - cur) * 32768, c + 1, t);
            const char* bb = Bsh + (size_t)cur * 32768;

            // non-owned tile (ti = 1-kt): partials -> LDS
            {
                f32x4 pn[2];
                tile_partial(bb + (size_t)(1 - kt) * 16384, ahi, alo, kt, lane, pn);
                char* xw = Xch + (size_t)cur * 16384 + rg * 4096 + kt * 2048;
                *(f32x4*)(xw + lane * 16)        = pn[0];
                *(f32x4*)(xw + 1024 + lane * 16) = pn[1];
            }
            // owned tile (ti = kt): keep partials in regs
            f32x4 po[2];
            tile_partial(bb + (size_t)kt * 16384, ahi, alo, kt, lane, po);

            __syncthreads();   // exchange visible; drains next-chunk staging

            const char* xr = Xch + (size_t)cur * 16384 + rg * 4096 + (1 - kt) * 2048;
            f32x4 pp0 = *(const f32x4*)(xr + lane * 16);
            f32x4 pp1 = *(const f32x4*)(xr + 1024 + lane * 16);

            const int col = c * 32 + kt * 16 + arow;
            const float wq = wql[col];
            #pragma unroll
            for (int i = 0; i < 4; ++i) {
                float c0 = po[0][i] + pp0[i];
                float d0 = (rsqC[0][i] - 2.f * c0) + wq;
                if (d0 < bestV[0][i]) { bestV[0][i] = d0; bestI[0][i] = col; }
                float c1 = po[1][i] + pp1[i];
                float d1 = (rsqC[1][i] - 2.f * c1) + wq;
                if (d1 < bestV[1][i]) { bestV[1][i] = d1; bestI[1][i] = col; }
            }
        }

        // ---- argmin: reduce across the 16 arow-lanes sharing each row-quad ----
        #pragma unroll
        for (int mi = 0; mi < 2; ++mi)
            #pragma unroll
            for (int i = 0; i < 4; ++i) {
                float bv = bestV[mi][i]; int bi = bestI[mi][i];
                #pragma unroll
                for (int s = 8; s; s >>= 1) {
                    float ov = __shfl_xor(bv, s, 16);
                    int   oi = __shfl_xor(bi, s, 16);
                    if (ov < bv || (ov == bv && oi < bi)) { bv = ov; bi = oi; }
                }
                bestV[mi][i] = bv; bestI[mi][i] = bi;
            }
        if (arow == 0) {
            #pragma unroll
            for (int mi = 0; mi < 2; ++mi)
                #pragma unroll
                for (int i = 0; i < 4; ++i) {
                    bV_sh[wv * 32 + mi * 16 + aq * 4 + i] = bestV[mi][i];
                    bI_sh[wv * 32 + mi * 16 + aq * 4 + i] = bestI[mi][i];
                }
        }
        __syncthreads();

        // ---- combine the two k-teams' col-halves per row, write index ----
        if (t < 128) {
            int rgi = t >> 5, rl = t & 31;
            float v0 = bV_sh[(rgi * 2 + 0) * 32 + rl]; int i0 = bI_sh[(rgi * 2 + 0) * 32 + rl];
            float v1 = bV_sh[(rgi * 2 + 1) * 32 + rl]; int i1 = bI_sh[(rgi * 2 + 1) * 32 + rl];
            int bi = (v1 < v0 || (v1 == v0 && i1 < i0)) ? i1 : i0;
            bidx_sh[t] = bi;
            out[NQ + (size_t)l * NROWS + rowB + t] = (float)bi;
        }
        // prefetch next layer's chunk 0 (independent of bidx) into buf 0
        if (l < NUM_LAYERS - 1)
            stage_chunk32(Fb + 2097152, Bsh, 0, t);
        __syncthreads();   // bidx_sh visible

        if (l < NUM_LAYERS - 1) {
            // ---- residual update in registers: r <- (hi+lo) - w, re-split ----
            #pragma unroll
            for (int mi = 0; mi < 2; ++mi) {
                const int bi = bidx_sh[rg * 32 + mi * 16 + arow];
                const float* wrow = Wl + (size_t)bi * DIM;
                float ns = 0.f;
                #pragma unroll
                for (int kq = 0; kq < 4; ++kq) {
                    const float* wp = wrow + (kt * 4 + kq) * 32 + aq * 8;
                    float4 w0 = *(const float4*)(wp);
                    float4 w1 = *(const float4*)(wp + 4);
                    float wv8[8] = {w0.x, w0.y, w0.z, w0.w, w1.x, w1.y, w1.z, w1.w};
                    #pragma unroll
                    for (int j = 0; j < 8; ++j) {
                        float r = ((float)ahi[mi][kq][j] + (float)alo[mi][kq][j]) - wv8[j];
                        _Float16 hv = (_Float16)r;
                        ahi[mi][kq][j] = hv;
                        alo[mi][kq][j] = (_Float16)(r - (float)hv);
                        ns = fmaf(r, r, ns);
                    }
                }
                s2[mi] = ns;
            }
        } else {
            // ---- final: out = h - (r2 - w3); each lane covers its k-half ----
            #pragma unroll
            for (int mi = 0; mi < 2; ++mi) {
                const int row = row0w + mi * 16 + arow;
                const int bi  = bidx_sh[rg * 32 + mi * 16 + arow];
                const float* wrow = Wl + (size_t)bi * DIM;
                #pragma unroll
                for (int kq = 0; kq < 4; ++kq) {
                    const int ko = (kt * 4 + kq) * 32 + aq * 8;
                    const float* wp = wrow + ko;
                    const float* hp = h + (size_t)row * DIM + ko;
                    float4 w0 = *(const float4*)(wp);
                    float4 w1 = *(const float4*)(wp + 4);
                    float4 h0 = *(const float4*)(hp);
                    float4 h1 = *(const float4*)(hp + 4);
                    float wv8[8] = {w0.x, w0.y, w0.z, w0.w, w1.x, w1.y, w1.z, w1.w};
                    float hv8[8] = {h0.x, h0.y, h0.z, h0.w, h1.x, h1.y, h1.z, h1.w};
                    float o[8];
                    #pragma unroll
                    for (int j = 0; j < 8; ++j) {
                        float r = ((float)ahi[mi][kq][j] + (float)alo[mi][kq][j]) - wv8[j];
                        o[j] = hv8[j] - r;
                    }
                    float* op = out + (size_t)row * DIM + ko;
                    *(float4*)(op)     = make_float4(o[0], o[1], o[2], o[3]);
                    *(float4*)(op + 4) = make_float4(o[4], o[5], o[6], o[7]);
                }
            }
        }
    }
}

extern "C" void kernel_launch(void* const* d_in, const int* in_sizes, int n_in,
                              void* d_out, int out_size, void* d_ws, size_t ws_size,
                              hipStream_t stream) {
    const float* h  = (const float*)d_in[0];
    const float* cb = (const float*)d_in[1];
    float* out = (float*)d_out;
    unsigned short* F = (unsigned short*)d_ws;
    float* wsq = (float*)((char*)d_ws + F_BYTES);

    hipFuncSetAttribute((const void*)rvq_main,
                        hipFuncAttributeMaxDynamicSharedMemorySize, SMEM_BYTES);

    rvq_wsq   <<<dim3(24),   dim3(256), 0, stream>>>(cb, wsq);
    rvq_repack<<<dim3(3072), dim3(64),  0, stream>>>(cb, F);
    rvq_main  <<<dim3(NROWS / 128), dim3(512), SMEM_BYTES, stream>>>(h, cb, F, wsq, out);
}